// Round 11
// baseline (29.251 us; speedup 1.0000x reference)
//
#include <hip/hip_runtime.h>

#define MH 28
#define MW 28
#define CC 64
#define GG 4
#define NB 32

typedef float vf4 __attribute__((ext_vector_type(4)));

// ws layout:
//   [0, 7168)           : uint2 slots[896] (overwritten every call, no init)
//   [8192, +100352)     : coarse mask, uchar (B,G,28,28)
//   [108544, +25088)    : any-of-g map, uchar (B,28,28)

// ---------------- D1: pool + project + gumbel decision ----------------
// grid: B*MH = 896 blocks (b, coarse row ch), 256 threads
// R9 structure (all 28 float4 batched in flight), but PLAIN loads (L2 path)
__global__ __launch_bounds__(256, 3) void masker_d1(
    const float* __restrict__ x, const float* __restrict__ w,
    const float* __restrict__ bias, const float* __restrict__ gum,
    unsigned char* __restrict__ coarse, unsigned char* __restrict__ anyb)
{
    int b = blockIdx.x / MH, ch = blockIdx.x % MH, t = threadIdx.x;
    __shared__ float pooled[CC][MW];
    __shared__ float wlds[8 * CC];
    __shared__ float logits[8][MW];
    __shared__ unsigned char mlds[GG][MW];

    // ---- prefetch small operands into registers before the big load phase ----
    float g0 = 0.f, g1 = 0.f, bo = 0.f;
    if (t < GG * MW) {
        int g = t / MW, cw = t - g * MW;
        g0 = gum[((((size_t)b * 2 + 0) * GG + g) * MH + ch) * MW + cw];
        g1 = gum[((((size_t)b * 2 + 1) * GG + g) * MH + ch) * MW + cw];
    }
    if (t < 8 * MW) bo = bias[t / MW];
    if (t < 128) ((float4*)wlds)[t] = ((const float4*)w)[t];

    // ---- phase 1: issue ALL 28 float4 loads (plain, L2-cached), then reduce ----
    const float* xb = x + (size_t)b * CC * 12544 + (size_t)(4 * ch) * 112;

    vf4 r[7][4];
    #pragma unroll
    for (int k = 0; k < 7; ++k) {
        int p  = t + 256 * k;              // 0..1791 = c(64) x cw(28)
        int c  = p / MW;
        int cw = p - c * MW;
        const vf4* base = (const vf4*)(xb + (size_t)c * 12544 + 4 * cw);
        #pragma unroll
        for (int hh = 0; hh < 4; ++hh)
            r[k][hh] = base[hh * 28];
    }
    #pragma unroll
    for (int k = 0; k < 7; ++k) {
        int p  = t + 256 * k;
        int c  = p / MW;
        int cw = p - c * MW;
        float s = 0.f;
        #pragma unroll
        for (int hh = 0; hh < 4; ++hh)
            s += r[k][hh].x + r[k][hh].y + r[k][hh].z + r[k][hh].w;
        pooled[c][cw] = s * 0.0625f;
    }
    __syncthreads();

    // ---- projection: 8 outputs x 28 cols ----
    if (t < 8 * MW) {
        int o = t / MW, cw = t - o * MW;
        float acc = bo;
        #pragma unroll
        for (int c = 0; c < CC; ++c)
            acc += pooled[c][cw] * wlds[o * CC + c];
        logits[o][cw] = acc;
    }
    __syncthreads();

    // ---- gumbel decision (T>0 scaling is argmax-invariant; ties -> idx 0) ----
    if (t < GG * MW) {
        int g = t / MW, cw = t - g * MW;
        unsigned char mv = (logits[g][cw] + g0 >= logits[g + 4][cw] + g1) ? 1u : 0u;
        mlds[g][cw] = mv;
        coarse[(((size_t)b * GG + g) * MH + ch) * MW + cw] = mv;
    }
    __syncthreads();
    if (t < MW)
        anyb[((size_t)b * MH + ch) * MW + t] =
            mlds[0][t] | mlds[1][t] | mlds[2][t] | mlds[3][t];
}

// ---------------- D2: upsample + dilate + outputs + per-block counts ----------------
// grid: 896 blocks, 256 threads (unchanged from R9: NT stores)
__global__ __launch_bounds__(256) void masker_d2(
    const unsigned char* __restrict__ coarse,
    const unsigned char* __restrict__ anyb,
    float* __restrict__ out_mask, float* __restrict__ out_dil,
    uint2* __restrict__ slots)
{
    int b = blockIdx.x / MH, ch = blockIdx.x % MH, t = threadIdx.x;
    __shared__ float carr[GG][MW];
    __shared__ float R[3][MW + 2];
    __shared__ unsigned int sm[4], sd[4];

    unsigned int local_m = 0;
    if (t < GG * MW) {
        int g = t / MW, cw = t - g * MW;
        unsigned char mv = coarse[(((size_t)b * GG + g) * MH + ch) * MW + cw];
        carr[g][cw] = (float)mv;
        local_m = mv;
    }
    if (t < MW) {
        float a  = (float)anyb[((size_t)b * MH + ch) * MW + t];
        float am = (ch > 0)      ? (float)anyb[((size_t)b * MH + ch - 1) * MW + t] : 0.f;
        float ap = (ch < MH - 1) ? (float)anyb[((size_t)b * MH + ch + 1) * MW + t] : 0.f;
        R[0][t + 1] = fmaxf(a, am);
        R[1][t + 1] = a;
        R[2][t + 1] = fmaxf(a, ap);
    }
    if (t < 3) { R[t][0] = 0.f; R[t][MW + 1] = 0.f; }
    __syncthreads();

    unsigned int local_d = 0;
    #pragma unroll
    for (int k = 0; k < 7; ++k) {
        int idx = t + 256 * k;             // g(4) x hh(4) x w(112)
        int g   = idx / 448;
        int rem = idx - g * 448;
        int hh  = rem / 112;
        int wfi = rem - hh * 112;
        int cw  = wfi >> 2;
        int wm  = wfi & 3;
        int rv  = (hh == 0) ? 0 : (hh == 3 ? 2 : 1);
        float d;
        if (wm == 0)      d = fmaxf(R[rv][cw],     R[rv][cw + 1]);
        else if (wm == 3) d = fmaxf(R[rv][cw + 1], R[rv][cw + 2]);
        else              d = R[rv][cw + 1];
        float mv = carr[g][cw];
        size_t o = (((size_t)b * GG + g) * 112 + (4 * ch + hh)) * 112 + wfi;
        __builtin_nontemporal_store(mv, &out_mask[o]);
        __builtin_nontemporal_store(d,  &out_dil[o]);
        local_d += (d > 0.5f) ? 1u : 0u;
    }

    // dual wave reduction, no atomics
    #pragma unroll
    for (int off = 32; off; off >>= 1) {
        local_m += __shfl_down(local_m, off);
        local_d += __shfl_down(local_d, off);
    }
    if ((t & 63) == 0) { sm[t >> 6] = local_m; sd[t >> 6] = local_d; }
    __syncthreads();
    if (t == 0) {
        uint2 v;
        v.x = sm[0] + sm[1] + sm[2] + sm[3];
        v.y = sd[0] + sd[1] + sd[2] + sd[3];
        slots[blockIdx.x] = v;             // overwrite: no init required
    }
}

// ---------------- D3: reduce 896 slots -> scalars ----------------
__global__ __launch_bounds__(256) void masker_d3(
    const uint2* __restrict__ slots, float* __restrict__ out_scalars)
{
    int t = threadIdx.x;
    unsigned int m = 0, d = 0;
    for (int i = t; i < NB * MH; i += 256) { uint2 v = slots[i]; m += v.x; d += v.y; }
    #pragma unroll
    for (int off = 32; off; off >>= 1) {
        m += __shfl_down(m, off);
        d += __shfl_down(d, off);
    }
    __shared__ unsigned int sm[4], sd[4];
    if ((t & 63) == 0) { sm[t >> 6] = m; sd[t >> 6] = d; }
    __syncthreads();
    if (t == 0) {
        out_scalars[0] = (float)(sm[0] + sm[1] + sm[2] + sm[3]) / 100352.0f;   // B*G*28*28
        out_scalars[1] = (float)(sd[0] + sd[1] + sd[2] + sd[3]) / 1605632.0f;  // B*G*112*112
        out_scalars[2] = 501760.0f;                                            // flops const
    }
}

extern "C" void kernel_launch(void* const* d_in, const int* in_sizes, int n_in,
                              void* d_out, int out_size, void* d_ws, size_t ws_size,
                              hipStream_t stream) {
    const float* x    = (const float*)d_in[0];
    const float* w    = (const float*)d_in[1];
    const float* bias = (const float*)d_in[2];
    const float* gum  = (const float*)d_in[3];

    float* out = (float*)d_out;
    const size_t n_mask = (size_t)NB * GG * 112 * 112;   // 1,605,632

    uint2*         slots  = (uint2*)d_ws;
    unsigned char* coarse = (unsigned char*)d_ws + 8192;
    unsigned char* anyb   = (unsigned char*)d_ws + 8192 + 100352;

    dim3 grid(NB * MH);
    masker_d1<<<grid, 256, 0, stream>>>(x, w, bias, gum, coarse, anyb);
    masker_d2<<<grid, 256, 0, stream>>>(coarse, anyb, out, out + n_mask, slots);
    masker_d3<<<1, 256, 0, stream>>>(slots, out + 2 * n_mask);
}

// Round 12
// 28.134 us; speedup vs baseline: 1.0397x; 1.0397x over previous
//
#include <hip/hip_runtime.h>

#define MH 28
#define MW 28
#define CC 64
#define GG 4
#define NB 32

typedef float vf4 __attribute__((ext_vector_type(4)));

// XCD-bijective swizzle: 896 blocks = 8 XCDs x 112. Consecutive hardware
// blockIdx round-robin across XCDs; this gives XCD k the contiguous logical
// range [k*112, (k+1)*112) = 4 complete batch images -> contiguous DRAM
// streams per XCD, and D1/D2 reuse of coarse/anyb lands in the local L2.
__device__ __forceinline__ int xcd_swizzle(int phys) {
    return (phys & 7) * 112 + (phys >> 3);
}

// ws layout:
//   [0, 7168)           : uint2 slots[896] (overwritten every call, no init)
//   [8192, +100352)     : coarse mask, uchar (B,G,28,28)
//   [108544, +25088)    : any-of-g map, uchar (B,28,28)

// ---------------- D1: pool + project + gumbel decision ----------------
// grid: B*MH = 896 blocks (b, coarse row ch), 256 threads
// R9 structure: all 28 NT float4 batched in flight
__global__ __launch_bounds__(256, 3) void masker_d1(
    const float* __restrict__ x, const float* __restrict__ w,
    const float* __restrict__ bias, const float* __restrict__ gum,
    unsigned char* __restrict__ coarse, unsigned char* __restrict__ anyb)
{
    const int blk = xcd_swizzle(blockIdx.x);
    int b = blk / MH, ch = blk - (blk / MH) * MH, t = threadIdx.x;
    __shared__ float pooled[CC][MW];
    __shared__ float wlds[8 * CC];
    __shared__ float logits[8][MW];
    __shared__ unsigned char mlds[GG][MW];

    // ---- prefetch small operands into registers before the big load phase ----
    float g0 = 0.f, g1 = 0.f, bo = 0.f;
    if (t < GG * MW) {
        int g = t / MW, cw = t - g * MW;
        g0 = gum[((((size_t)b * 2 + 0) * GG + g) * MH + ch) * MW + cw];
        g1 = gum[((((size_t)b * 2 + 1) * GG + g) * MH + ch) * MW + cw];
    }
    if (t < 8 * MW) bo = bias[t / MW];
    if (t < 128) ((float4*)wlds)[t] = ((const float4*)w)[t];

    // ---- phase 1: issue ALL 28 NT float4 loads, then reduce ----
    const float* xb = x + (size_t)b * CC * 12544 + (size_t)(4 * ch) * 112;

    vf4 r[7][4];
    #pragma unroll
    for (int k = 0; k < 7; ++k) {
        int p  = t + 256 * k;              // 0..1791 = c(64) x cw(28)
        int c  = p / MW;
        int cw = p - c * MW;
        const vf4* base = (const vf4*)(xb + (size_t)c * 12544 + 4 * cw);
        #pragma unroll
        for (int hh = 0; hh < 4; ++hh)
            r[k][hh] = __builtin_nontemporal_load(base + hh * 28);
    }
    #pragma unroll
    for (int k = 0; k < 7; ++k) {
        int p  = t + 256 * k;
        int c  = p / MW;
        int cw = p - c * MW;
        float s = 0.f;
        #pragma unroll
        for (int hh = 0; hh < 4; ++hh)
            s += r[k][hh].x + r[k][hh].y + r[k][hh].z + r[k][hh].w;
        pooled[c][cw] = s * 0.0625f;
    }
    __syncthreads();

    // ---- projection: 8 outputs x 28 cols ----
    if (t < 8 * MW) {
        int o = t / MW, cw = t - o * MW;
        float acc = bo;
        #pragma unroll
        for (int c = 0; c < CC; ++c)
            acc += pooled[c][cw] * wlds[o * CC + c];
        logits[o][cw] = acc;
    }
    __syncthreads();

    // ---- gumbel decision (T>0 scaling is argmax-invariant; ties -> idx 0) ----
    if (t < GG * MW) {
        int g = t / MW, cw = t - g * MW;
        unsigned char mv = (logits[g][cw] + g0 >= logits[g + 4][cw] + g1) ? 1u : 0u;
        mlds[g][cw] = mv;
        coarse[(((size_t)b * GG + g) * MH + ch) * MW + cw] = mv;
    }
    __syncthreads();
    if (t < MW)
        anyb[((size_t)b * MH + ch) * MW + t] =
            mlds[0][t] | mlds[1][t] | mlds[2][t] | mlds[3][t];
}

// ---------------- D2: upsample + dilate + outputs + per-block counts ----------------
// grid: 896 blocks, 256 threads; same swizzle as D1 -> coarse/anyb are local-L2 hits
__global__ __launch_bounds__(256) void masker_d2(
    const unsigned char* __restrict__ coarse,
    const unsigned char* __restrict__ anyb,
    float* __restrict__ out_mask, float* __restrict__ out_dil,
    uint2* __restrict__ slots)
{
    const int blk = xcd_swizzle(blockIdx.x);
    int b = blk / MH, ch = blk - (blk / MH) * MH, t = threadIdx.x;
    __shared__ float carr[GG][MW];
    __shared__ float R[3][MW + 2];
    __shared__ unsigned int sm[4], sd[4];

    unsigned int local_m = 0;
    if (t < GG * MW) {
        int g = t / MW, cw = t - g * MW;
        unsigned char mv = coarse[(((size_t)b * GG + g) * MH + ch) * MW + cw];
        carr[g][cw] = (float)mv;
        local_m = mv;
    }
    if (t < MW) {
        float a  = (float)anyb[((size_t)b * MH + ch) * MW + t];
        float am = (ch > 0)      ? (float)anyb[((size_t)b * MH + ch - 1) * MW + t] : 0.f;
        float ap = (ch < MH - 1) ? (float)anyb[((size_t)b * MH + ch + 1) * MW + t] : 0.f;
        R[0][t + 1] = fmaxf(a, am);
        R[1][t + 1] = a;
        R[2][t + 1] = fmaxf(a, ap);
    }
    if (t < 3) { R[t][0] = 0.f; R[t][MW + 1] = 0.f; }
    __syncthreads();

    unsigned int local_d = 0;
    #pragma unroll
    for (int k = 0; k < 7; ++k) {
        int idx = t + 256 * k;             // g(4) x hh(4) x w(112)
        int g   = idx / 448;
        int rem = idx - g * 448;
        int hh  = rem / 112;
        int wfi = rem - hh * 112;
        int cw  = wfi >> 2;
        int wm  = wfi & 3;
        int rv  = (hh == 0) ? 0 : (hh == 3 ? 2 : 1);
        float d;
        if (wm == 0)      d = fmaxf(R[rv][cw],     R[rv][cw + 1]);
        else if (wm == 3) d = fmaxf(R[rv][cw + 1], R[rv][cw + 2]);
        else              d = R[rv][cw + 1];
        float mv = carr[g][cw];
        size_t o = (((size_t)b * GG + g) * 112 + (4 * ch + hh)) * 112 + wfi;
        __builtin_nontemporal_store(mv, &out_mask[o]);
        __builtin_nontemporal_store(d,  &out_dil[o]);
        local_d += (d > 0.5f) ? 1u : 0u;
    }

    // dual wave reduction, no atomics
    #pragma unroll
    for (int off = 32; off; off >>= 1) {
        local_m += __shfl_down(local_m, off);
        local_d += __shfl_down(local_d, off);
    }
    if ((t & 63) == 0) { sm[t >> 6] = local_m; sd[t >> 6] = local_d; }
    __syncthreads();
    if (t == 0) {
        uint2 v;
        v.x = sm[0] + sm[1] + sm[2] + sm[3];
        v.y = sd[0] + sd[1] + sd[2] + sd[3];
        slots[blk] = v;                    // overwrite: no init required
    }
}

// ---------------- D3: reduce 896 slots -> scalars ----------------
__global__ __launch_bounds__(256) void masker_d3(
    const uint2* __restrict__ slots, float* __restrict__ out_scalars)
{
    int t = threadIdx.x;
    unsigned int m = 0, d = 0;
    for (int i = t; i < NB * MH; i += 256) { uint2 v = slots[i]; m += v.x; d += v.y; }
    #pragma unroll
    for (int off = 32; off; off >>= 1) {
        m += __shfl_down(m, off);
        d += __shfl_down(d, off);
    }
    __shared__ unsigned int sm[4], sd[4];
    if ((t & 63) == 0) { sm[t >> 6] = m; sd[t >> 6] = d; }
    __syncthreads();
    if (t == 0) {
        out_scalars[0] = (float)(sm[0] + sm[1] + sm[2] + sm[3]) / 100352.0f;   // B*G*28*28
        out_scalars[1] = (float)(sd[0] + sd[1] + sd[2] + sd[3]) / 1605632.0f;  // B*G*112*112
        out_scalars[2] = 501760.0f;                                            // flops const
    }
}

extern "C" void kernel_launch(void* const* d_in, const int* in_sizes, int n_in,
                              void* d_out, int out_size, void* d_ws, size_t ws_size,
                              hipStream_t stream) {
    const float* x    = (const float*)d_in[0];
    const float* w    = (const float*)d_in[1];
    const float* bias = (const float*)d_in[2];
    const float* gum  = (const float*)d_in[3];

    float* out = (float*)d_out;
    const size_t n_mask = (size_t)NB * GG * 112 * 112;   // 1,605,632

    uint2*         slots  = (uint2*)d_ws;
    unsigned char* coarse = (unsigned char*)d_ws + 8192;
    unsigned char* anyb   = (unsigned char*)d_ws + 8192 + 100352;

    dim3 grid(NB * MH);
    masker_d1<<<grid, 256, 0, stream>>>(x, w, bias, gum, coarse, anyb);
    masker_d2<<<grid, 256, 0, stream>>>(coarse, anyb, out, out + n_mask, slots);
    masker_d3<<<1, 256, 0, stream>>>(slots, out + 2 * n_mask);
}